// Round 15
// baseline (52.692 us; speedup 1.0000x reference)
//
#include <hip/hip_runtime.h>
#include <hip/hip_bf16.h>

typedef float f32x4 __attribute__((ext_vector_type(4)));

namespace {
constexpr int kB = 4;
constexpr int kT = 4096;
constexpr int kC = 8;
constexpr int kN = kB * kT;            // 16384 tokens
constexpr int kTRows = 64;             // t-rows per block band (proven optimum)
constexpr int kSPerThread = 4;         // s-cols per thread (f32x4 store)
constexpr int kBlockThreads = 256;
constexpr int kWaves = kBlockThreads / 64;
constexpr int kSTile = kBlockThreads * kSPerThread;  // 1024 s-cols
}

// softmax without max-subtraction: logits are N(0,1); exp safe in fp32.
__device__ __forceinline__ void softmax8_nomax(const float e[kC], float p[kC]) {
    float sum = 0.f;
#pragma unroll
    for (int i = 0; i < kC; ++i) { p[i] = __expf(e[i]); sum += p[i]; }
    float inv = __builtin_amdgcn_rcpf(sum);
#pragma unroll
    for (int i = 0; i < kC; ++i) p[i] *= inv;
}

// Kernel 1 (minimal): q[i] = softmax(emb[token_ids[i]]). One token per
// thread, 16384 threads in one round (256 blocks x 64 thr = 1 wave/CU),
// no matvec (moved to mask's t-side where it's 16x cheaper). This kernel
// absorbs ALL random gathers; mask reads only the coalesced q-table.
__global__ __launch_bounds__(64) void dam_prep(const int* __restrict__ token_ids,
                                               const float* __restrict__ emb,
                                               float* __restrict__ q_ws) {
    const int i = blockIdx.x * 64 + threadIdx.x;
    const int tok = token_ids[i];
    const f32x4* row = reinterpret_cast<const f32x4*>(emb) + (size_t)tok * 2;
    f32x4 e0 = row[0], e1 = row[1];
    float e[kC] = {e0.x, e0.y, e0.z, e0.w, e1.x, e1.y, e1.z, e1.w};
    float q[kC];
    softmax8_nomax(e, q);
    f32x4* qo = reinterpret_cast<f32x4*>(q_ws) + (size_t)i * 2;
    qo[0] = f32x4{q[0], q[1], q[2], q[3]};
    qo[1] = f32x4{q[4], q[5], q[6], q[7]};
}

// Kernel 2: barrier-free mask (R13 structure), coalesced q-table reads.
// Block = 64 t-rows x 1024 s-cols (1024 blocks, 4/CU). Each wave builds its
// private w-table (w_t = -(C^T q_t), one row per lane) in its own LDS
// region; wave-internal LDS RAW needs only lgkmcnt -> no __syncthreads.
__global__ __launch_bounds__(256) void dam_mask(const float* __restrict__ q_ws,
                                                const float* __restrict__ cmat,
                                                float* __restrict__ out) {
    const int b = blockIdx.z;
    const int t0 = blockIdx.y * kTRows;
    const int s0 = blockIdx.x * kSTile;
    const int tid = threadIdx.x;
    const int wid = tid >> 6;
    const int lane = tid & 63;

    __shared__ f32x4 w_lds[kWaves][kTRows * 2];   // per-wave copies, 8 KB

    // ---- coalesced loads: t-side q row (2KB/wave contiguous) ----
    const f32x4* qt = reinterpret_cast<const f32x4*>(q_ws) + ((size_t)(b * kT + t0)) * 2;
    f32x4 pe0 = qt[lane * 2 + 0];
    f32x4 pe1 = qt[lane * 2 + 1];

    // ---- coalesced loads: s-side q rows (16B x 8 per thread, sequential) ----
    const int s = s0 + tid * kSPerThread;
    const f32x4* qs = reinterpret_cast<const f32x4*>(q_ws) + ((size_t)(b * kT) + s) * 2;
    f32x4 se[kSPerThread * 2];
#pragma unroll
    for (int k = 0; k < kSPerThread * 2; ++k) se[k] = qs[k];

    // ---- t-side: w = -(C^T q_t) -> per-wave LDS ----
    {
        float p[kC] = {pe0.x, pe0.y, pe0.z, pe0.w, pe1.x, pe1.y, pe1.z, pe1.w};
        float w[kC];
#pragma unroll
        for (int c = 0; c < kC; ++c) {
            float acc = 0.f;
#pragma unroll
            for (int d = 0; d < kC; ++d) acc = fmaf(cmat[d * kC + c], p[d], acc);  // C^T
            w[c] = -acc;
        }
        w_lds[wid][lane * 2 + 0] = f32x4{w[0], w[1], w[2], w[3]};
        w_lds[wid][lane * 2 + 1] = f32x4{w[4], w[5], w[6], w[7]};
    }
    // NO __syncthreads: only same-wave lanes read this region (lgkmcnt order).

    float q[kSPerThread][kC];
#pragma unroll
    for (int j = 0; j < kSPerThread; ++j) {
        f32x4 a = se[j * 2 + 0];
        f32x4 c = se[j * 2 + 1];
        q[j][0] = a.x; q[j][1] = a.y; q[j][2] = a.z; q[j][3] = a.w;
        q[j][4] = c.x; q[j][5] = c.y; q[j][6] = c.z; q[j][7] = c.w;
    }

    // ---- main loop: 64 rows x 4 cols per thread ----
    float* orow = out + ((size_t)(b * kT + t0)) * kT + s;
#pragma unroll 4
    for (int tt = 0; tt < kTRows; ++tt) {
        f32x4 w0 = w_lds[wid][tt * 2 + 0];
        f32x4 w1 = w_lds[wid][tt * 2 + 1];
        float wr[kC] = {w0.x, w0.y, w0.z, w0.w, w1.x, w1.y, w1.z, w1.w};
        float r[kSPerThread];
#pragma unroll
        for (int j = 0; j < kSPerThread; ++j) {
            float acc = 0.f;   // acc = -compat
#pragma unroll
            for (int i = 0; i < kC; ++i) acc = fmaf(wr[i], q[j][i], acc);
            // 2*sigmoid(-acc)-1 = (1 - e^acc) / (1 + e^acc)
            float ex = __expf(acc);
            r[j] = (1.f - ex) * __builtin_amdgcn_rcpf(1.f + ex);
        }
        f32x4 ov = {r[0], r[1], r[2], r[3]};
        *reinterpret_cast<f32x4*>(orow + (size_t)tt * kT) = ov;
    }
}

extern "C" void kernel_launch(void* const* d_in, const int* in_sizes, int n_in,
                              void* d_out, int out_size, void* d_ws, size_t ws_size,
                              hipStream_t stream) {
    const int* token_ids = (const int*)d_in[0];
    const float* emb     = (const float*)d_in[1];
    const float* cmat    = (const float*)d_in[2];
    float* out  = (float*)d_out;
    float* q_ws = (float*)d_ws;                      // kN*8 floats (0.5 MB)

    dam_prep<<<kN / 64, 64, 0, stream>>>(token_ids, emb, q_ws);
    dim3 grid(kT / kSTile, kT / kTRows, kB);         // (4, 64, 4) = 1024 blocks
    dam_mask<<<grid, kBlockThreads, 0, stream>>>(q_ws, cmat, out);
}

// Round 16
// 49.717 us; speedup vs baseline: 1.0598x; 1.0598x over previous
//
#include <hip/hip_runtime.h>
#include <hip/hip_bf16.h>

typedef float f32x4 __attribute__((ext_vector_type(4)));

namespace {
constexpr int kB = 4;
constexpr int kT = 4096;
constexpr int kC = 8;
constexpr int kTRows = 64;             // t-rows per block band (proven optimum)
constexpr int kSPerThread = 4;         // s-cols per thread (f32x4 store)
constexpr int kBlockThreads = 256;
constexpr int kSTile = kBlockThreads * kSPerThread;  // 1024 s-cols
}

// softmax without max-subtraction: logits are N(0,1); exp safe in fp32.
__device__ __forceinline__ void softmax8_nomax(const float e[kC], float p[kC]) {
    float sum = 0.f;
#pragma unroll
    for (int i = 0; i < kC; ++i) { p[i] = __expf(e[i]); sum += p[i]; }
    float inv = __builtin_amdgcn_rcpf(sum);
#pragma unroll
    for (int i = 0; i < kC; ++i) p[i] *= inv;
}

// Fused: block = 64 t-rows x 1024 s-cols (1024 blocks, 4/CU, 16 waves/CU).
// SHARED w-table: wave 0 alone gathers the 64 t-rows and builds
// w_t = -(C^T softmax(emb[tok_t])) in LDS (t-gathers cut 4x vs per-wave
// copies). Other waves overlap the barrier wait with their s-side
// gather+softmax. Single __syncthreads (~0.4us, R12-measured).
__global__ __launch_bounds__(256) void dam_fused(const int* __restrict__ token_ids,
                                                 const float* __restrict__ emb,
                                                 const float* __restrict__ cmat,
                                                 float* __restrict__ out) {
    const int b = blockIdx.z;
    const int t0 = blockIdx.y * kTRows;
    const int s0 = blockIdx.x * kSTile;
    const int tid = threadIdx.x;

    __shared__ f32x4 w_lds[kTRows * 2];   // one shared table, 2 KB

    // ---- t-gathers: wave 0 only, issued first (longest chain) ----
    f32x4 pe0, pe1;
    if (tid < kTRows) {
        int tokT = token_ids[b * kT + t0 + tid];
        const f32x4* prow = reinterpret_cast<const f32x4*>(emb) + (size_t)tokT * 2;
        pe0 = prow[0];
        pe1 = prow[1];
    }

    // ---- s-gathers: all threads ----
    const int s = s0 + tid * kSPerThread;
    int4 toks = *reinterpret_cast<const int4*>(&token_ids[b * kT + s]);
    int tokS[kSPerThread] = {toks.x, toks.y, toks.z, toks.w};
    f32x4 se[kSPerThread][2];
#pragma unroll
    for (int j = 0; j < kSPerThread; ++j) {
        const f32x4* srow = reinterpret_cast<const f32x4*>(emb) + (size_t)tokS[j] * 2;
        se[j][0] = srow[0];
        se[j][1] = srow[1];
    }

    // ---- t-side (wave 0): w = -(C^T p) -> shared LDS ----
    if (tid < kTRows) {
        float e[kC] = {pe0.x, pe0.y, pe0.z, pe0.w, pe1.x, pe1.y, pe1.z, pe1.w};
        float p[kC];
        softmax8_nomax(e, p);
        float w[kC];
#pragma unroll
        for (int c = 0; c < kC; ++c) {
            float acc = 0.f;
#pragma unroll
            for (int d = 0; d < kC; ++d) acc = fmaf(cmat[d * kC + c], p[d], acc);  // C^T
            w[c] = -acc;
        }
        w_lds[tid * 2 + 0] = f32x4{w[0], w[1], w[2], w[3]};
        w_lds[tid * 2 + 1] = f32x4{w[4], w[5], w[6], w[7]};
    }

    // ---- s-phase (all threads, overlaps wave 0's t-chain) ----
    float q[kSPerThread][kC];
#pragma unroll
    for (int j = 0; j < kSPerThread; ++j) {
        float e[kC] = {se[j][0].x, se[j][0].y, se[j][0].z, se[j][0].w,
                       se[j][1].x, se[j][1].y, se[j][1].z, se[j][1].w};
        softmax8_nomax(e, q[j]);
    }

    __syncthreads();

    // ---- main loop: 64 rows x 4 cols per thread ----
    float* orow = out + ((size_t)(b * kT + t0)) * kT + s;
#pragma unroll 4
    for (int tt = 0; tt < kTRows; ++tt) {
        f32x4 w0 = w_lds[tt * 2 + 0];
        f32x4 w1 = w_lds[tt * 2 + 1];
        float wr[kC] = {w0.x, w0.y, w0.z, w0.w, w1.x, w1.y, w1.z, w1.w};
        float r[kSPerThread];
#pragma unroll
        for (int j = 0; j < kSPerThread; ++j) {
            float acc = 0.f;   // acc = -compat
#pragma unroll
            for (int i = 0; i < kC; ++i) acc = fmaf(wr[i], q[j][i], acc);
            // 2*sigmoid(-acc)-1 = (1 - e^acc) / (1 + e^acc)
            float ex = __expf(acc);
            r[j] = (1.f - ex) * __builtin_amdgcn_rcpf(1.f + ex);
        }
        f32x4 ov = {r[0], r[1], r[2], r[3]};
        *reinterpret_cast<f32x4*>(orow + (size_t)tt * kT) = ov;
    }
}

extern "C" void kernel_launch(void* const* d_in, const int* in_sizes, int n_in,
                              void* d_out, int out_size, void* d_ws, size_t ws_size,
                              hipStream_t stream) {
    const int* token_ids = (const int*)d_in[0];
    const float* emb     = (const float*)d_in[1];
    const float* cmat    = (const float*)d_in[2];
    float* out = (float*)d_out;

    dim3 grid(kT / kSTile, kT / kTRows, kB);   // (4, 64, 4) = 1024 blocks
    dam_fused<<<grid, kBlockThreads, 0, stream>>>(token_ids, emb, cmat, out);
}